// Round 6
// baseline (302.563 us; speedup 1.0000x reference)
//
#include <hip/hip_runtime.h>
#include <hip/hip_bf16.h>
#include <cstddef>

#define NN 50000
#define EE 800000
#define TE 850000   // EE + NN self loops
#define INC 256
#define C1 128      // heads(2) * hid(64)
#define C2 64
#define NCHUNK 49   // ceil(NN/1024)

// block-range dispatch for merged kernels
#define NB_COUNT 3321   // ceil(TE/256)
#define NB_CAST  3125   // NN*INC/4 float4s / 4 per thread / 256 threads
#define NB_P1    256
#define NB_P2    128
#define NB_K1    (NB_COUNT + NB_CAST + NB_P1 + NB_P2)
#define NB_GEMM1 782    // 391*2 (128x128 tiles over 50000x256)
#define NB_K2    (NB_GEMM1 + NB_COUNT)

#define LOG2E 1.44269504088896340736f

typedef unsigned short ushort_t;
typedef short bf16x8 __attribute__((ext_vector_type(8)));
typedef float f32x4 __attribute__((ext_vector_type(4)));

__device__ inline ushort_t bf16r(float f) {  // RNE float->bf16
    unsigned u = __float_as_uint(f);
    unsigned r = (u + 0x7fffu + ((u >> 16) & 1u)) >> 16;
    return (ushort_t)r;
}
#define LOF(u) (__uint_as_float((u) << 16))           // low bf16 of packed uint
#define HIF(u) (__uint_as_float((u) & 0xffff0000u))   // high bf16 of packed uint
#define ELU(t) ((t) > 0.f ? (t) : (__expf(t) - 1.f))

// ---------------- scans (serial dependency, small) ----------------

__global__ void k_scan1(const int* __restrict__ deg, int* __restrict__ incl,
                        int* __restrict__ totals) {
    __shared__ int lds[1024];
    int t = threadIdx.x;
    int i = blockIdx.x * 1024 + t;
    int v = (i < NN) ? deg[i] : 0;
    lds[t] = v;
    __syncthreads();
    for (int off = 1; off < 1024; off <<= 1) {
        int add = (t >= off) ? lds[t - off] : 0;
        __syncthreads();
        lds[t] += add;
        __syncthreads();
    }
    if (i < NN) incl[i] = lds[t];
    if (t == 1023) totals[blockIdx.x] = lds[t];
}

// scan3: chunk offset via one wave-reduce over totals (was: 48 serial dependent
// global loads per thread -> latency chain; now: 1 coalesced load + 6 shuffles).
__global__ void k_scan3(const int* __restrict__ incl, const int* __restrict__ deg,
                        const int* __restrict__ totals, int* __restrict__ rowstart) {
    __shared__ int sOff;
    int chunk = blockIdx.x >> 2;  // 256-thread blocks, 1024-wide chunks
    if (threadIdx.x < 64) {
        int t = (threadIdx.x < chunk) ? totals[threadIdx.x] : 0;
#pragma unroll
        for (int o = 1; o <= 32; o <<= 1) t += __shfl_xor(t, o, 64);
        if (threadIdx.x == 0) sOff = t;
    }
    __syncthreads();
    int i = blockIdx.x * blockDim.x + threadIdx.x;
    if (i == 0) rowstart[NN] = TE;
    if (i >= NN) return;
    rowstart[i] = incl[i] - deg[i] + sOff;
}

// ---------------- K1: count+rank | cast | prep_w1 | prep_w2 (independent stages) ----------------
// Count blocks FIRST: atomic wall starts at full width; bandwidth-light cast/prep
// hide underneath it. (Rounds 1-2 proved MFMA GEMM does NOT coexist with the wall.)
// Cast: 4 float4 loads in flight per thread (MLP=4).

__global__ __launch_bounds__(256) void k_stage1(
    const int* __restrict__ ei, int* __restrict__ deg, int* __restrict__ rank,
    const float* __restrict__ x, ushort_t* __restrict__ xb,
    const float* __restrict__ W1l, const float* __restrict__ W1r,
    const float* __restrict__ b1l, const float* __restrict__ b1r,
    ushort_t* __restrict__ Wt1, float* __restrict__ biasf1,
    const float* __restrict__ W2l, const float* __restrict__ W2r,
    const float* __restrict__ b2l, const float* __restrict__ b2r,
    ushort_t* __restrict__ Wt2, float* __restrict__ biasf2) {
    int b = blockIdx.x;
    int tid = threadIdx.x;
    if (b < NB_COUNT) {
        // count + per-edge rank (rank write coalesced)
        int e = b * 256 + tid;
        if (e < TE) {
            int dst = (e < EE) ? ei[EE + e] : (e - EE);
            rank[e] = atomicAdd(&deg[dst], 1);
        }
    } else if (b < NB_COUNT + NB_CAST) {
        // fp32 -> bf16 cast of x, four float4s per thread (strided by 256 for coalescing)
        int i0 = (b - NB_COUNT) * 1024 + tid;
        float4 a[4];
#pragma unroll
        for (int k = 0; k < 4; k++) a[k] = ((const float4*)x)[i0 + k * 256];
#pragma unroll
        for (int k = 0; k < 4; k++) {
            ushort4 o;
            o.x = bf16r(a[k].x); o.y = bf16r(a[k].y);
            o.z = bf16r(a[k].z); o.w = bf16r(a[k].w);
            ((ushort4*)xb)[i0 + k * 256] = o;
        }
    } else if (b < NB_COUNT + NB_CAST + NB_P1) {
        // prep W1: Wt1[n][k], n in [0,256), K=256, HALF=128
        int n = b - NB_COUNT - NB_CAST;
        int k = tid;
        const float* W = (n < 128) ? W1l : W1r;
        int c = (n < 128) ? n : n - 128;
        Wt1[(size_t)n * 256 + k] = bf16r(W[(size_t)k * 128 + c]);
        if (n == 0) biasf1[k] = (k < 128) ? b1l[k] : b1r[k - 128];
    } else {
        // prep W2: Wt2[n][k], n in [0,128), K=128, HALF=64
        int n = b - NB_COUNT - NB_CAST - NB_P1;
        int k = tid;
        if (k < 128) {
            const float* W = (n < 64) ? W2l : W2r;
            int c = (n < 64) ? n : n - 64;
            Wt2[(size_t)n * 128 + k] = bf16r(W[(size_t)k * 64 + c]);
            if (n == 0) biasf2[k] = (k < 64) ? b2l[k] : b2r[k - 64];
        }
    }
}

// ---------------- bf16 MFMA GEMM body ----------------
// C[M,NCOL](bf16) = A[M,K](bf16) @ Bt[NCOL,K]^T + bias(fp32)
// 128x128 tile, BK=32, 256 threads, 16x16x32 MFMA; LDS rows padded to 40 bf16.

template <int K, int NCOL>
__device__ inline void gemm_body(const ushort_t* __restrict__ A,
                                 const ushort_t* __restrict__ Bt,
                                 const float* __restrict__ bias,
                                 ushort_t* __restrict__ C, int M,
                                 int bm, int bn, ushort_t* As, ushort_t* Bs) {
    int tid = threadIdx.x;
    int w = tid >> 6, l = tid & 63;
    int wm = (w & 1) * 64, wn = (w >> 1) * 64;
    int lm = l & 15, half = l >> 4;

    f32x4 zero = {0.f, 0.f, 0.f, 0.f};
    f32x4 acc[4][4];
#pragma unroll
    for (int a = 0; a < 4; a++)
#pragma unroll
        for (int b = 0; b < 4; b++) acc[a][b] = zero;

    for (int k0 = 0; k0 < K; k0 += 32) {
#pragma unroll
        for (int q = 0; q < 2; q++) {
            int seg = q * 256 + tid;
            int m = seg >> 2;
            int ko = (seg & 3) * 8;
            *(float4*)&As[m * 40 + ko] = *(const float4*)&A[(size_t)(bm + m) * K + k0 + ko];
            *(float4*)&Bs[m * 40 + ko] = *(const float4*)&Bt[(size_t)(bn + m) * K + k0 + ko];
        }
        __syncthreads();
        bf16x8 af[4], bfr[4];
#pragma unroll
        for (int mi = 0; mi < 4; mi++)
            af[mi] = *(const bf16x8*)&As[(wm + mi * 16 + lm) * 40 + half * 8];
#pragma unroll
        for (int ni = 0; ni < 4; ni++)
            bfr[ni] = *(const bf16x8*)&Bs[(wn + ni * 16 + lm) * 40 + half * 8];
#pragma unroll
        for (int mi = 0; mi < 4; mi++)
#pragma unroll
            for (int ni = 0; ni < 4; ni++)
                acc[mi][ni] = __builtin_amdgcn_mfma_f32_16x16x32_bf16(
                    af[mi], bfr[ni], acc[mi][ni], 0, 0, 0);
        __syncthreads();
    }
#pragma unroll
    for (int ni = 0; ni < 4; ni++) {
        int col = bn + wn + ni * 16 + lm;
        float bv = bias[col];
#pragma unroll
        for (int mi = 0; mi < 4; mi++) {
            int rbase = bm + wm + mi * 16 + half * 4;
#pragma unroll
            for (int r = 0; r < 4; r++) {
                int row = rbase + r;
                if (row < M) C[(size_t)row * NCOL + col] = bf16r(acc[mi][ni][r] + bv);
            }
        }
    }
}

// ---------------- K2: GEMM layer-1 | scatter (independent) ----------------

__global__ __launch_bounds__(256) void k_gemm1_scatter(
    const ushort_t* __restrict__ A, const ushort_t* __restrict__ Bt,
    const float* __restrict__ bias, ushort_t* __restrict__ C,
    const int* __restrict__ ei, const int* __restrict__ rank,
    const int* __restrict__ rowstart, int* __restrict__ ssrc) {
    __shared__ __align__(16) ushort_t As[128 * 40];
    __shared__ __align__(16) ushort_t Bs[128 * 40];
    int b = blockIdx.x;
    if (b < NB_GEMM1) {
        int bm = (b >> 1) * 128;
        int bn = (b & 1) * 128;
        gemm_body<256, 256>(A, Bt, bias, C, NN, bm, bn, As, Bs);
    } else {
        // atomic-free scatter: one independent 4B random store per edge
        int e = (b - NB_GEMM1) * 256 + threadIdx.x;
        if (e < TE) {
            int s, d;
            if (e < EE) { s = ei[e]; d = ei[EE + e]; }
            else        { s = e - EE; d = s; }
            ssrc[rowstart[d] + rank[e]] = s;
        }
    }
}

__global__ __launch_bounds__(256) void k_gemm2(
    const ushort_t* __restrict__ A, const ushort_t* __restrict__ Bt,
    const float* __restrict__ bias, ushort_t* __restrict__ C) {
    __shared__ __align__(16) ushort_t As[128 * 40];
    __shared__ __align__(16) ushort_t Bs[128 * 40];
    int bm = blockIdx.x * 128;
    gemm_body<128, 128>(A, Bt, bias, C, NN, bm, 0, As, Bs);
}

// ---------------- Fused GATv2 layer 1 ----------------
// Round-0 structure + one-iteration software prefetch in the main loop:
// next ssrc reads issue before the logit phase, next gathers before the
// shuffle/exp/acc phase -> gather latency hides under current-iter VALU.
// att*lrelu(t) = (0.6att)t + (0.4att)|t|; att pre-scaled by log2e -> p=exp2f(d).

__global__ __launch_bounds__(256) void k_fused1(
    const ushort_t* __restrict__ xlr, const int* __restrict__ rowstart,
    const int* __restrict__ ssrc, const float* __restrict__ att,
    const float* __restrict__ bias,
    const float* __restrict__ g, const float* __restrict__ b,
    const float* __restrict__ m, const float* __restrict__ v,
    ushort_t* __restrict__ out) {
    int lane = threadIdx.x & 63;
    int i = blockIdx.x * 4 + (threadIdx.x >> 6);
    if (i >= NN) return;
    int hw = lane >> 5;
    int c2 = lane & 31;
    uint2 xru = *(const uint2*)&xlr[(size_t)i * 256 + 128 + 4 * c2];
    float xr0 = LOF(xru.x), xr1 = HIF(xru.x), xr2 = LOF(xru.y), xr3 = HIF(xru.y);
    float4 at = *(const float4*)&att[4 * c2];
    float4 a6 = make_float4(at.x * (0.6f * LOG2E), at.y * (0.6f * LOG2E),
                            at.z * (0.6f * LOG2E), at.w * (0.6f * LOG2E));
    float4 a4 = make_float4(at.x * (0.4f * LOG2E), at.y * (0.4f * LOG2E),
                            at.z * (0.4f * LOG2E), at.w * (0.4f * LOG2E));
    int row = rowstart[i], end = rowstart[i + 1];
    float a0 = 0.f, a1 = 0.f, a2 = 0.f, a3 = 0.f, s = 0.f;
    int j = row;
    int src[4];
    uint2 u[4];
    if (j + 8 <= end) {
#pragma unroll
        for (int k = 0; k < 4; k++) src[k] = ssrc[j + 2 * k + hw];
#pragma unroll
        for (int k = 0; k < 4; k++)
            u[k] = *(const uint2*)&xlr[(size_t)src[k] * 256 + 4 * c2];
    }
    for (; j + 8 <= end; j += 8) {
        bool more = (j + 16 <= end);
        int srcn[4];
        if (more) {
#pragma unroll
            for (int k = 0; k < 4; k++) srcn[k] = ssrc[j + 8 + 2 * k + hw];
        }
        float d[4], f0[4], f1[4], f2[4], f3[4];
#pragma unroll
        for (int k = 0; k < 4; k++) {
            f0[k] = LOF(u[k].x); f1[k] = HIF(u[k].x);
            f2[k] = LOF(u[k].y); f3[k] = HIF(u[k].y);
            float t0 = f0[k] + xr0, t1 = f1[k] + xr1;
            float t2 = f2[k] + xr2, t3 = f3[k] + xr3;
            float dd = fmaf(a6.x, t0, a4.x * fabsf(t0));
            dd = fmaf(a6.y, t1, fmaf(a4.y, fabsf(t1), dd));
            dd = fmaf(a6.z, t2, fmaf(a4.z, fabsf(t2), dd));
            dd = fmaf(a6.w, t3, fmaf(a4.w, fabsf(t3), dd));
            d[k] = dd;
        }
        if (more) {
#pragma unroll
            for (int k = 0; k < 4; k++)
                u[k] = *(const uint2*)&xlr[(size_t)srcn[k] * 256 + 4 * c2];
        }
#pragma unroll
        for (int o = 1; o <= 8; o <<= 1) {
#pragma unroll
            for (int k = 0; k < 4; k++) d[k] += __shfl_xor(d[k], o, 64);
        }
#pragma unroll
        for (int k = 0; k < 4; k++) {
            float p = exp2f(d[k]);
            a0 += p * f0[k]; a1 += p * f1[k];
            a2 += p * f2[k]; a3 += p * f3[k];
            s += p;
        }
    }
    for (; j < end; j += 2) {
        int je = j + hw;
        bool valid = je < end;
        int sr = valid ? ssrc[je] : i;
        uint2 uu = *(const uint2*)&xlr[(size_t)sr * 256 + 4 * c2];
        float f0 = LOF(uu.x), f1 = HIF(uu.x), f2 = LOF(uu.y), f3 = HIF(uu.y);
        float t0 = f0 + xr0, t1 = f1 + xr1, t2 = f2 + xr2, t3 = f3 + xr3;
        float dd = fmaf(a6.x, t0, a4.x * fabsf(t0));
        dd = fmaf(a6.y, t1, fmaf(a4.y, fabsf(t1), dd));
        dd = fmaf(a6.z, t2, fmaf(a4.z, fabsf(t2), dd));
        dd = fmaf(a6.w, t3, fmaf(a4.w, fabsf(t3), dd));
        dd += __shfl_xor(dd, 1, 64);
        dd += __shfl_xor(dd, 2, 64);
        dd += __shfl_xor(dd, 4, 64);
        dd += __shfl_xor(dd, 8, 64);
        float p = valid ? exp2f(dd) : 0.f;
        a0 += p * f0; a1 += p * f1; a2 += p * f2; a3 += p * f3;
        s += p;
    }
    // combine the two half-wave edge slots (channels replicated across hw)
    a0 += __shfl_xor(a0, 32, 64);
    a1 += __shfl_xor(a1, 32, 64);
    a2 += __shfl_xor(a2, 32, 64);
    a3 += __shfl_xor(a3, 32, 64);
    s  += __shfl_xor(s, 32, 64);
    if (hw == 0) {
        float inv = 1.f / s;
        float4 bb = *(const float4*)&bias[4 * c2];
        float4 mm = *(const float4*)&m[4 * c2];
        float4 vv = *(const float4*)&v[4 * c2];
        float4 gg = *(const float4*)&g[4 * c2];
        float4 b2 = *(const float4*)&b[4 * c2];
        float o0 = a0 * inv + bb.x, o1 = a1 * inv + bb.y;
        float o2 = a2 * inv + bb.z, o3 = a3 * inv + bb.w;
        o0 = (o0 - mm.x) * rsqrtf(vv.x + 1e-5f) * gg.x + b2.x;
        o1 = (o1 - mm.y) * rsqrtf(vv.y + 1e-5f) * gg.y + b2.y;
        o2 = (o2 - mm.z) * rsqrtf(vv.z + 1e-5f) * gg.z + b2.z;
        o3 = (o3 - mm.w) * rsqrtf(vv.w + 1e-5f) * gg.w + b2.w;
        o0 = ELU(o0); o1 = ELU(o1); o2 = ELU(o2); o3 = ELU(o3);
        uint2 wp;
        wp.x = (unsigned)bf16r(o0) | ((unsigned)bf16r(o1) << 16);
        wp.y = (unsigned)bf16r(o2) | ((unsigned)bf16r(o3) << 16);
        *(uint2*)&out[(size_t)i * C1 + 4 * c2] = wp;
    }
}

// Layer 2 + classifier: one wave per node; lane covers 4 of 64 channels (c4=lane&15),
// quarter-wave qw is an edge slot. 16-edge main loop (MLP=4) with one-iteration
// prefetch; 8-edge step and 4-edge remainder keep tail granularity.
__global__ __launch_bounds__(256) void k_fused2(
    const ushort_t* __restrict__ xlr, const int* __restrict__ rowstart,
    const int* __restrict__ ssrc, const float* __restrict__ att,
    const float* __restrict__ bias,
    const float* __restrict__ g, const float* __restrict__ b,
    const float* __restrict__ m, const float* __restrict__ v,
    const float* __restrict__ Wc, const float* __restrict__ bc,
    float* __restrict__ out) {
    int lane = threadIdx.x & 63;
    int i = blockIdx.x * 4 + (threadIdx.x >> 6);
    if (i >= NN) return;
    int qw = lane >> 4;
    int c4 = lane & 15;
    uint2 xru = *(const uint2*)&xlr[(size_t)i * 128 + 64 + 4 * c4];
    float xr0 = LOF(xru.x), xr1 = HIF(xru.x), xr2 = LOF(xru.y), xr3 = HIF(xru.y);
    float4 at = *(const float4*)&att[4 * c4];
    float4 a6 = make_float4(at.x * (0.6f * LOG2E), at.y * (0.6f * LOG2E),
                            at.z * (0.6f * LOG2E), at.w * (0.6f * LOG2E));
    float4 a4 = make_float4(at.x * (0.4f * LOG2E), at.y * (0.4f * LOG2E),
                            at.z * (0.4f * LOG2E), at.w * (0.4f * LOG2E));
    int row = rowstart[i], end = rowstart[i + 1];
    float a0 = 0.f, a1 = 0.f, a2 = 0.f, a3 = 0.f, s = 0.f;
    int j = row;
    int src[4];
    uint2 u[4];
    if (j + 16 <= end) {
#pragma unroll
        for (int k = 0; k < 4; k++) src[k] = ssrc[j + 4 * k + qw];
#pragma unroll
        for (int k = 0; k < 4; k++)
            u[k] = *(const uint2*)&xlr[(size_t)src[k] * 128 + 4 * c4];
    }
    for (; j + 16 <= end; j += 16) {
        bool more = (j + 32 <= end);
        int srcn[4];
        if (more) {
#pragma unroll
            for (int k = 0; k < 4; k++) srcn[k] = ssrc[j + 16 + 4 * k + qw];
        }
        float d[4], f0[4], f1[4], f2[4], f3[4];
#pragma unroll
        for (int k = 0; k < 4; k++) {
            f0[k] = LOF(u[k].x); f1[k] = HIF(u[k].x);
            f2[k] = LOF(u[k].y); f3[k] = HIF(u[k].y);
            float t0 = f0[k] + xr0, t1 = f1[k] + xr1;
            float t2 = f2[k] + xr2, t3 = f3[k] + xr3;
            float dd = fmaf(a6.x, t0, a4.x * fabsf(t0));
            dd = fmaf(a6.y, t1, fmaf(a4.y, fabsf(t1), dd));
            dd = fmaf(a6.z, t2, fmaf(a4.z, fabsf(t2), dd));
            dd = fmaf(a6.w, t3, fmaf(a4.w, fabsf(t3), dd));
            d[k] = dd;
        }
        if (more) {
#pragma unroll
            for (int k = 0; k < 4; k++)
                u[k] = *(const uint2*)&xlr[(size_t)srcn[k] * 128 + 4 * c4];
        }
#pragma unroll
        for (int o = 1; o <= 8; o <<= 1) {
#pragma unroll
            for (int k = 0; k < 4; k++) d[k] += __shfl_xor(d[k], o, 64);
        }
#pragma unroll
        for (int k = 0; k < 4; k++) {
            float p = exp2f(d[k]);
            a0 += p * f0[k]; a1 += p * f1[k];
            a2 += p * f2[k]; a3 += p * f3[k];
            s += p;
        }
    }
    if (j + 8 <= end) {
        int src2[2];
        uint2 u2[2];
#pragma unroll
        for (int k = 0; k < 2; k++) src2[k] = ssrc[j + 4 * k + qw];
#pragma unroll
        for (int k = 0; k < 2; k++)
            u2[k] = *(const uint2*)&xlr[(size_t)src2[k] * 128 + 4 * c4];
#pragma unroll
        for (int k = 0; k < 2; k++) {
            float f0 = LOF(u2[k].x), f1 = HIF(u2[k].x), f2 = LOF(u2[k].y), f3 = HIF(u2[k].y);
            float t0 = f0 + xr0, t1 = f1 + xr1, t2 = f2 + xr2, t3 = f3 + xr3;
            float dd = fmaf(a6.x, t0, a4.x * fabsf(t0));
            dd = fmaf(a6.y, t1, fmaf(a4.y, fabsf(t1), dd));
            dd = fmaf(a6.z, t2, fmaf(a4.z, fabsf(t2), dd));
            dd = fmaf(a6.w, t3, fmaf(a4.w, fabsf(t3), dd));
            dd += __shfl_xor(dd, 1, 64);
            dd += __shfl_xor(dd, 2, 64);
            dd += __shfl_xor(dd, 4, 64);
            dd += __shfl_xor(dd, 8, 64);
            float p = exp2f(dd);
            a0 += p * f0; a1 += p * f1; a2 += p * f2; a3 += p * f3;
            s += p;
        }
        j += 8;
    }
    for (; j < end; j += 4) {
        int je = j + qw;
        bool valid = je < end;
        int sr = valid ? ssrc[je] : i;
        uint2 uu = *(const uint2*)&xlr[(size_t)sr * 128 + 4 * c4];
        float f0 = LOF(uu.x), f1 = HIF(uu.x), f2 = LOF(uu.y), f3 = HIF(uu.y);
        float t0 = f0 + xr0, t1 = f1 + xr1, t2 = f2 + xr2, t3 = f3 + xr3;
        float dd = fmaf(a6.x, t0, a4.x * fabsf(t0));
        dd = fmaf(a6.y, t1, fmaf(a4.y, fabsf(t1), dd));
        dd = fmaf(a6.z, t2, fmaf(a4.z, fabsf(t2), dd));
        dd = fmaf(a6.w, t3, fmaf(a4.w, fabsf(t3), dd));
        dd += __shfl_xor(dd, 1, 64);
        dd += __shfl_xor(dd, 2, 64);
        dd += __shfl_xor(dd, 4, 64);
        dd += __shfl_xor(dd, 8, 64);
        float p = valid ? exp2f(dd) : 0.f;
        a0 += p * f0; a1 += p * f1; a2 += p * f2; a3 += p * f3;
        s += p;
    }
    // combine the 4 quarter-wave edge slots
#pragma unroll
    for (int o = 16; o <= 32; o <<= 1) {
        a0 += __shfl_xor(a0, o, 64);
        a1 += __shfl_xor(a1, o, 64);
        a2 += __shfl_xor(a2, o, 64);
        a3 += __shfl_xor(a3, o, 64);
        s  += __shfl_xor(s, o, 64);
    }
    float inv = 1.f / s;
    float4 bb = *(const float4*)&bias[4 * c4];
    float4 mm = *(const float4*)&m[4 * c4];
    float4 vv = *(const float4*)&v[4 * c4];
    float4 gg = *(const float4*)&g[4 * c4];
    float4 b2 = *(const float4*)&b[4 * c4];
    float o0 = a0 * inv + bb.x, o1 = a1 * inv + bb.y;
    float o2 = a2 * inv + bb.z, o3 = a3 * inv + bb.w;
    o0 = (o0 - mm.x) * rsqrtf(vv.x + 1e-5f) * gg.x + b2.x;
    o1 = (o1 - mm.y) * rsqrtf(vv.y + 1e-5f) * gg.y + b2.y;
    o2 = (o2 - mm.z) * rsqrtf(vv.z + 1e-5f) * gg.z + b2.z;
    o3 = (o3 - mm.w) * rsqrtf(vv.w + 1e-5f) * gg.w + b2.w;
    o0 = ELU(o0); o1 = ELU(o1); o2 = ELU(o2); o3 = ELU(o3);
    float4 wc = *(const float4*)&Wc[4 * c4];
    float z = o0 * wc.x + o1 * wc.y + o2 * wc.z + o3 * wc.w;
    z += __shfl_xor(z, 1, 64);
    z += __shfl_xor(z, 2, 64);
    z += __shfl_xor(z, 4, 64);
    z += __shfl_xor(z, 8, 64);
    if (lane == 0) out[i] = 1.f / (1.f + __expf(-(z + bc[0])));
}

// ---------------- launch ----------------

extern "C" void kernel_launch(void* const* d_in, const int* in_sizes, int n_in,
                              void* d_out, int out_size, void* d_ws, size_t ws_size,
                              hipStream_t stream) {
    const float* x    = (const float*)d_in[0];
    const int*   ei   = (const int*)d_in[1];
    const float* W1l  = (const float*)d_in[2];
    const float* b1l  = (const float*)d_in[3];
    const float* W1r  = (const float*)d_in[4];
    const float* b1r  = (const float*)d_in[5];
    const float* att1 = (const float*)d_in[6];
    const float* bias1= (const float*)d_in[7];
    const float* bn1g = (const float*)d_in[8];
    const float* bn1b = (const float*)d_in[9];
    const float* bn1m = (const float*)d_in[10];
    const float* bn1v = (const float*)d_in[11];
    const float* W2l  = (const float*)d_in[12];
    const float* b2l  = (const float*)d_in[13];
    const float* W2r  = (const float*)d_in[14];
    const float* b2r  = (const float*)d_in[15];
    const float* att2 = (const float*)d_in[16];
    const float* bias2= (const float*)d_in[17];
    const float* bn2g = (const float*)d_in[18];
    const float* bn2b = (const float*)d_in[19];
    const float* bn2m = (const float*)d_in[20];
    const float* bn2v = (const float*)d_in[21];
    const float* Wc   = (const float*)d_in[22];
    const float* bc   = (const float*)d_in[23];
    float* out = (float*)d_out;

    char* ws = (char*)d_ws;
    size_t off = 0;
    auto alloc = [&](size_t bytes) {
        size_t o = off;
        off += (bytes + 255) & ~(size_t)255;
        return o;
    };
    ushort_t* xb    = (ushort_t*)(ws + alloc((size_t)(NN + 128) * 256 * 2));
    ushort_t* xlr1  = (ushort_t*)(ws + alloc((size_t)NN * 256 * 2));  // reused as xlr2
    ushort_t* h1b   = (ushort_t*)(ws + alloc((size_t)(NN + 128) * 128 * 2));
    ushort_t* Wt1   = (ushort_t*)(ws + alloc((size_t)256 * 256 * 2));
    float*    biasf1= (float*)(ws + alloc(256 * 4));
    ushort_t* Wt2   = (ushort_t*)(ws + alloc((size_t)128 * 128 * 2));
    float*    biasf2= (float*)(ws + alloc(128 * 4));
    int* deg      = (int*)(ws + alloc((size_t)NN * 4));
    int* incl     = (int*)(ws + alloc((size_t)NN * 4));
    int* rowstart = (int*)(ws + alloc((size_t)(NN + 1) * 4));
    int* totals   = (int*)(ws + alloc(64 * 4));
    int* rank     = (int*)(ws + alloc((size_t)TE * 4));
    int* ssrc     = (int*)(ws + alloc((size_t)TE * 4));
    ushort_t* xlr2 = xlr1;

    // deg = 0 (memset instead of a kernel)
    hipMemsetAsync(deg, 0, (size_t)NN * 4, stream);

    // K1: count+rank | cast x->bf16 | prep W1 | prep W2 (all independent)
    k_stage1<<<NB_K1, 256, 0, stream>>>(ei, deg, rank, x, xb,
                                        W1l, W1r, b1l, b1r, Wt1, biasf1,
                                        W2l, W2r, b2l, b2r, Wt2, biasf2);

    // scans (serial, small; scan2 folded into scan3)
    k_scan1<<<NCHUNK, 1024, 0, stream>>>(deg, incl, totals);
    k_scan3<<<(NN + 255) / 256, 256, 0, stream>>>(incl, deg, totals, rowstart);

    // K2: GEMM layer-1 | scatter (independent; gemm blocks first)
    k_gemm1_scatter<<<NB_K2, 256, 0, stream>>>(xb, Wt1, biasf1, xlr1,
                                               ei, rank, rowstart, ssrc);

    // layer 1 fused
    k_fused1<<<(NN + 3) / 4, 256, 0, stream>>>(xlr1, rowstart, ssrc, att1, bias1,
                                               bn1g, bn1b, bn1m, bn1v, h1b);

    // layer 2 (+classifier)
    k_gemm2<<<(NN + 127) / 128, 256, 0, stream>>>(h1b, Wt2, biasf2, xlr2);
    k_fused2<<<(NN + 3) / 4, 256, 0, stream>>>(xlr2, rowstart, ssrc, att2, bias2,
                                               bn2g, bn2b, bn2m, bn2v, Wc, bc, out);
}

// Round 7
// 292.284 us; speedup vs baseline: 1.0352x; 1.0352x over previous
//
#include <hip/hip_runtime.h>
#include <hip/hip_bf16.h>
#include <cstddef>

#define NN 50000
#define EE 800000
#define TE 850000   // EE + NN self loops
#define INC 256
#define C1 128      // heads(2) * hid(64)
#define C2 64
#define NCHUNK 49   // ceil(NN/1024)
#define NREP 8      // XCD-sharded histogram replicas

// block-range dispatch for merged kernels
#define NB_COUNT 3321   // ceil(TE/256)
#define NB_CAST  3125   // NN*INC/4 float4s / 4 per thread / 256 threads
#define NB_P1    256
#define NB_P2    128
#define NB_K1    (NB_COUNT + NB_CAST + NB_P1 + NB_P2)
#define NB_GEMM1 782    // 391*2 (128x128 tiles over 50000x256)
#define NB_K2    (NB_GEMM1 + NB_COUNT)

#define LOG2E 1.44269504088896340736f

typedef unsigned short ushort_t;
typedef short bf16x8 __attribute__((ext_vector_type(8)));
typedef float f32x4 __attribute__((ext_vector_type(4)));

__device__ inline ushort_t bf16r(float f) {  // RNE float->bf16
    unsigned u = __float_as_uint(f);
    unsigned r = (u + 0x7fffu + ((u >> 16) & 1u)) >> 16;
    return (ushort_t)r;
}
#define LOF(u) (__uint_as_float((u) << 16))           // low bf16 of packed uint
#define HIF(u) (__uint_as_float((u) & 0xffff0000u))   // high bf16 of packed uint
#define ELU(t) ((t) > 0.f ? (t) : (__expf(t) - 1.f))

// ---------------- scans (serial dependency, small) ----------------

// scan1: per-node total degree = sum of 8 replicas; block-wide inclusive scan.
__global__ void k_scan1(const int* __restrict__ deg8, int* __restrict__ degt,
                        int* __restrict__ incl, int* __restrict__ totals) {
    __shared__ int lds[1024];
    int t = threadIdx.x;
    int i = blockIdx.x * 1024 + t;
    int v = 0;
    if (i < NN) {
#pragma unroll
        for (int r = 0; r < NREP; r++) v += deg8[r * NN + i];
        degt[i] = v;
    }
    lds[t] = v;
    __syncthreads();
    for (int off = 1; off < 1024; off <<= 1) {
        int add = (t >= off) ? lds[t - off] : 0;
        __syncthreads();
        lds[t] += add;
        __syncthreads();
    }
    if (i < NN) incl[i] = lds[t];
    if (t == 1023) totals[blockIdx.x] = lds[t];
}

// scan3: chunk offset via one wave-reduce over totals; emits rowstart and
// per-replica scatter bases off8[r][i] = rowstart[i] + sum_{r'<r} deg8[r'][i].
__global__ void k_scan3(const int* __restrict__ incl, const int* __restrict__ degt,
                        const int* __restrict__ deg8, const int* __restrict__ totals,
                        int* __restrict__ rowstart, int* __restrict__ off8) {
    __shared__ int sOff;
    int chunk = blockIdx.x >> 2;  // 256-thread blocks, 1024-wide chunks
    if (threadIdx.x < 64) {
        int t = (threadIdx.x < chunk) ? totals[threadIdx.x] : 0;
#pragma unroll
        for (int o = 1; o <= 32; o <<= 1) t += __shfl_xor(t, o, 64);
        if (threadIdx.x == 0) sOff = t;
    }
    __syncthreads();
    int i = blockIdx.x * blockDim.x + threadIdx.x;
    if (i == 0) rowstart[NN] = TE;
    if (i >= NN) return;
    int base = incl[i] - degt[i] + sOff;
    rowstart[i] = base;
#pragma unroll
    for (int r = 0; r < NREP; r++) {
        off8[r * NN + i] = base;
        base += deg8[r * NN + i];
    }
}

// ---------------- K1: count+rank | cast | prep_w1 | prep_w2 (independent stages) ----------------
// Count blocks FIRST. XCD-sharded histogram: replica = block & 7 -> 8x less
// per-address contention, replica lines mostly XCD-local (dispatch round-robin).
// Cast: 4 float4 loads in flight per thread (MLP=4).

__global__ __launch_bounds__(256) void k_stage1(
    const int* __restrict__ ei, int* __restrict__ deg8, int* __restrict__ rank,
    const float* __restrict__ x, ushort_t* __restrict__ xb,
    const float* __restrict__ W1l, const float* __restrict__ W1r,
    const float* __restrict__ b1l, const float* __restrict__ b1r,
    ushort_t* __restrict__ Wt1, float* __restrict__ biasf1,
    const float* __restrict__ W2l, const float* __restrict__ W2r,
    const float* __restrict__ b2l, const float* __restrict__ b2r,
    ushort_t* __restrict__ Wt2, float* __restrict__ biasf2) {
    int b = blockIdx.x;
    int tid = threadIdx.x;
    if (b < NB_COUNT) {
        // count + per-edge rank within replica (rank write coalesced)
        int e = b * 256 + tid;
        if (e < TE) {
            int dst = (e < EE) ? ei[EE + e] : (e - EE);
            rank[e] = atomicAdd(&deg8[(b & 7) * NN + dst], 1);
        }
    } else if (b < NB_COUNT + NB_CAST) {
        // fp32 -> bf16 cast of x, four float4s per thread (strided by 256 for coalescing)
        int i0 = (b - NB_COUNT) * 1024 + tid;
        float4 a[4];
#pragma unroll
        for (int k = 0; k < 4; k++) a[k] = ((const float4*)x)[i0 + k * 256];
#pragma unroll
        for (int k = 0; k < 4; k++) {
            ushort4 o;
            o.x = bf16r(a[k].x); o.y = bf16r(a[k].y);
            o.z = bf16r(a[k].z); o.w = bf16r(a[k].w);
            ((ushort4*)xb)[i0 + k * 256] = o;
        }
    } else if (b < NB_COUNT + NB_CAST + NB_P1) {
        // prep W1: Wt1[n][k], n in [0,256), K=256, HALF=128
        int n = b - NB_COUNT - NB_CAST;
        int k = tid;
        const float* W = (n < 128) ? W1l : W1r;
        int c = (n < 128) ? n : n - 128;
        Wt1[(size_t)n * 256 + k] = bf16r(W[(size_t)k * 128 + c]);
        if (n == 0) biasf1[k] = (k < 128) ? b1l[k] : b1r[k - 128];
    } else {
        // prep W2: Wt2[n][k], n in [0,128), K=128, HALF=64
        int n = b - NB_COUNT - NB_CAST - NB_P1;
        int k = tid;
        if (k < 128) {
            const float* W = (n < 64) ? W2l : W2r;
            int c = (n < 64) ? n : n - 64;
            Wt2[(size_t)n * 128 + k] = bf16r(W[(size_t)k * 64 + c]);
            if (n == 0) biasf2[k] = (k < 64) ? b2l[k] : b2r[k - 64];
        }
    }
}

// ---------------- bf16 MFMA GEMM body ----------------
// C[M,NCOL](bf16) = A[M,K](bf16) @ Bt[NCOL,K]^T + bias(fp32)
// 128x128 tile, BK=32, 256 threads, 16x16x32 MFMA; LDS rows padded to 40 bf16.

template <int K, int NCOL>
__device__ inline void gemm_body(const ushort_t* __restrict__ A,
                                 const ushort_t* __restrict__ Bt,
                                 const float* __restrict__ bias,
                                 ushort_t* __restrict__ C, int M,
                                 int bm, int bn, ushort_t* As, ushort_t* Bs) {
    int tid = threadIdx.x;
    int w = tid >> 6, l = tid & 63;
    int wm = (w & 1) * 64, wn = (w >> 1) * 64;
    int lm = l & 15, half = l >> 4;

    f32x4 zero = {0.f, 0.f, 0.f, 0.f};
    f32x4 acc[4][4];
#pragma unroll
    for (int a = 0; a < 4; a++)
#pragma unroll
        for (int b = 0; b < 4; b++) acc[a][b] = zero;

    for (int k0 = 0; k0 < K; k0 += 32) {
#pragma unroll
        for (int q = 0; q < 2; q++) {
            int seg = q * 256 + tid;
            int m = seg >> 2;
            int ko = (seg & 3) * 8;
            *(float4*)&As[m * 40 + ko] = *(const float4*)&A[(size_t)(bm + m) * K + k0 + ko];
            *(float4*)&Bs[m * 40 + ko] = *(const float4*)&Bt[(size_t)(bn + m) * K + k0 + ko];
        }
        __syncthreads();
        bf16x8 af[4], bfr[4];
#pragma unroll
        for (int mi = 0; mi < 4; mi++)
            af[mi] = *(const bf16x8*)&As[(wm + mi * 16 + lm) * 40 + half * 8];
#pragma unroll
        for (int ni = 0; ni < 4; ni++)
            bfr[ni] = *(const bf16x8*)&Bs[(wn + ni * 16 + lm) * 40 + half * 8];
#pragma unroll
        for (int mi = 0; mi < 4; mi++)
#pragma unroll
            for (int ni = 0; ni < 4; ni++)
                acc[mi][ni] = __builtin_amdgcn_mfma_f32_16x16x32_bf16(
                    af[mi], bfr[ni], acc[mi][ni], 0, 0, 0);
        __syncthreads();
    }
#pragma unroll
    for (int ni = 0; ni < 4; ni++) {
        int col = bn + wn + ni * 16 + lm;
        float bv = bias[col];
#pragma unroll
        for (int mi = 0; mi < 4; mi++) {
            int rbase = bm + wm + mi * 16 + half * 4;
#pragma unroll
            for (int r = 0; r < 4; r++) {
                int row = rbase + r;
                if (row < M) C[(size_t)row * NCOL + col] = bf16r(acc[mi][ni][r] + bv);
            }
        }
    }
}

// ---------------- K2: GEMM layer-1 | scatter (independent) ----------------

__global__ __launch_bounds__(256) void k_gemm1_scatter(
    const ushort_t* __restrict__ A, const ushort_t* __restrict__ Bt,
    const float* __restrict__ bias, ushort_t* __restrict__ C,
    const int* __restrict__ ei, const int* __restrict__ rank,
    const int* __restrict__ off8, int* __restrict__ ssrc) {
    __shared__ __align__(16) ushort_t As[128 * 40];
    __shared__ __align__(16) ushort_t Bs[128 * 40];
    int b = blockIdx.x;
    if (b < NB_GEMM1) {
        int bm = (b >> 1) * 128;
        int bn = (b & 1) * 128;
        gemm_body<256, 256>(A, Bt, bias, C, NN, bm, bn, As, Bs);
    } else {
        // atomic-free scatter: replica base + within-replica rank
        int e = (b - NB_GEMM1) * 256 + threadIdx.x;
        if (e < TE) {
            int s, d;
            if (e < EE) { s = ei[e]; d = ei[EE + e]; }
            else        { s = e - EE; d = s; }
            int r = (e >> 8) & 7;  // replica = count-block & 7
            ssrc[off8[r * NN + d] + rank[e]] = s;
        }
    }
}

__global__ __launch_bounds__(256) void k_gemm2(
    const ushort_t* __restrict__ A, const ushort_t* __restrict__ Bt,
    const float* __restrict__ bias, ushort_t* __restrict__ C) {
    __shared__ __align__(16) ushort_t As[128 * 40];
    __shared__ __align__(16) ushort_t Bs[128 * 40];
    int bm = blockIdx.x * 128;
    gemm_body<128, 128>(A, Bt, bias, C, NN, bm, 0, As, Bs);
}

// ---------------- Fused GATv2 layer (R5-proven structure, unchanged) ----------------
// att*lrelu(t) = (0.6att)t + (0.4att)|t| (abs is a free VOP3 input modifier);
// att pre-scaled by log2e so p = exp2f(d) is a single v_exp_f32.

__global__ __launch_bounds__(256) void k_fused1(
    const ushort_t* __restrict__ xlr, const int* __restrict__ rowstart,
    const int* __restrict__ ssrc, const float* __restrict__ att,
    const float* __restrict__ bias,
    const float* __restrict__ g, const float* __restrict__ b,
    const float* __restrict__ m, const float* __restrict__ v,
    ushort_t* __restrict__ out) {
    int lane = threadIdx.x & 63;
    int i = blockIdx.x * 4 + (threadIdx.x >> 6);
    if (i >= NN) return;
    int hw = lane >> 5;
    int c2 = lane & 31;
    uint2 xru = *(const uint2*)&xlr[(size_t)i * 256 + 128 + 4 * c2];
    float xr0 = LOF(xru.x), xr1 = HIF(xru.x), xr2 = LOF(xru.y), xr3 = HIF(xru.y);
    float4 at = *(const float4*)&att[4 * c2];
    float4 a6 = make_float4(at.x * (0.6f * LOG2E), at.y * (0.6f * LOG2E),
                            at.z * (0.6f * LOG2E), at.w * (0.6f * LOG2E));
    float4 a4 = make_float4(at.x * (0.4f * LOG2E), at.y * (0.4f * LOG2E),
                            at.z * (0.4f * LOG2E), at.w * (0.4f * LOG2E));
    int row = rowstart[i], end = rowstart[i + 1];
    float a0 = 0.f, a1 = 0.f, a2 = 0.f, a3 = 0.f, s = 0.f;
    int j = row;
    for (; j + 8 <= end; j += 8) {
        int src[4];
        uint2 u[4];
#pragma unroll
        for (int k = 0; k < 4; k++) src[k] = ssrc[j + 2 * k + hw];
#pragma unroll
        for (int k = 0; k < 4; k++)
            u[k] = *(const uint2*)&xlr[(size_t)src[k] * 256 + 4 * c2];
        float d[4], f0[4], f1[4], f2[4], f3[4];
#pragma unroll
        for (int k = 0; k < 4; k++) {
            f0[k] = LOF(u[k].x); f1[k] = HIF(u[k].x);
            f2[k] = LOF(u[k].y); f3[k] = HIF(u[k].y);
            float t0 = f0[k] + xr0, t1 = f1[k] + xr1;
            float t2 = f2[k] + xr2, t3 = f3[k] + xr3;
            float dd = fmaf(a6.x, t0, a4.x * fabsf(t0));
            dd = fmaf(a6.y, t1, fmaf(a4.y, fabsf(t1), dd));
            dd = fmaf(a6.z, t2, fmaf(a4.z, fabsf(t2), dd));
            dd = fmaf(a6.w, t3, fmaf(a4.w, fabsf(t3), dd));
            d[k] = dd;
        }
#pragma unroll
        for (int o = 1; o <= 8; o <<= 1) {
#pragma unroll
            for (int k = 0; k < 4; k++) d[k] += __shfl_xor(d[k], o, 64);
        }
#pragma unroll
        for (int k = 0; k < 4; k++) {
            float p = exp2f(d[k]);
            a0 += p * f0[k]; a1 += p * f1[k];
            a2 += p * f2[k]; a3 += p * f3[k];
            s += p;
        }
    }
    for (; j < end; j += 2) {
        int je = j + hw;
        bool valid = je < end;
        int src = valid ? ssrc[je] : i;
        uint2 uu = *(const uint2*)&xlr[(size_t)src * 256 + 4 * c2];
        float f0 = LOF(uu.x), f1 = HIF(uu.x), f2 = LOF(uu.y), f3 = HIF(uu.y);
        float t0 = f0 + xr0, t1 = f1 + xr1, t2 = f2 + xr2, t3 = f3 + xr3;
        float dd = fmaf(a6.x, t0, a4.x * fabsf(t0));
        dd = fmaf(a6.y, t1, fmaf(a4.y, fabsf(t1), dd));
        dd = fmaf(a6.z, t2, fmaf(a4.z, fabsf(t2), dd));
        dd = fmaf(a6.w, t3, fmaf(a4.w, fabsf(t3), dd));
        dd += __shfl_xor(dd, 1, 64);
        dd += __shfl_xor(dd, 2, 64);
        dd += __shfl_xor(dd, 4, 64);
        dd += __shfl_xor(dd, 8, 64);
        float p = valid ? exp2f(dd) : 0.f;
        a0 += p * f0; a1 += p * f1; a2 += p * f2; a3 += p * f3;
        s += p;
    }
    // combine the two half-wave edge slots (channels replicated across hw)
    a0 += __shfl_xor(a0, 32, 64);
    a1 += __shfl_xor(a1, 32, 64);
    a2 += __shfl_xor(a2, 32, 64);
    a3 += __shfl_xor(a3, 32, 64);
    s  += __shfl_xor(s, 32, 64);
    if (hw == 0) {
        float inv = 1.f / s;
        float4 bb = *(const float4*)&bias[4 * c2];
        float4 mm = *(const float4*)&m[4 * c2];
        float4 vv = *(const float4*)&v[4 * c2];
        float4 gg = *(const float4*)&g[4 * c2];
        float4 b2 = *(const float4*)&b[4 * c2];
        float o0 = a0 * inv + bb.x, o1 = a1 * inv + bb.y;
        float o2 = a2 * inv + bb.z, o3 = a3 * inv + bb.w;
        o0 = (o0 - mm.x) * rsqrtf(vv.x + 1e-5f) * gg.x + b2.x;
        o1 = (o1 - mm.y) * rsqrtf(vv.y + 1e-5f) * gg.y + b2.y;
        o2 = (o2 - mm.z) * rsqrtf(vv.z + 1e-5f) * gg.z + b2.z;
        o3 = (o3 - mm.w) * rsqrtf(vv.w + 1e-5f) * gg.w + b2.w;
        o0 = ELU(o0); o1 = ELU(o1); o2 = ELU(o2); o3 = ELU(o3);
        uint2 wp;
        wp.x = (unsigned)bf16r(o0) | ((unsigned)bf16r(o1) << 16);
        wp.y = (unsigned)bf16r(o2) | ((unsigned)bf16r(o3) << 16);
        *(uint2*)&out[(size_t)i * C1 + 4 * c2] = wp;
    }
}

// Layer 2 + classifier: one wave per node; lane covers 4 of 64 channels (c4=lane&15),
// quarter-wave qw is an edge slot. 16-edge main loop (MLP=4), 8-edge step,
// 4-edge remainder (R5-proven).
__global__ __launch_bounds__(256) void k_fused2(
    const ushort_t* __restrict__ xlr, const int* __restrict__ rowstart,
    const int* __restrict__ ssrc, const float* __restrict__ att,
    const float* __restrict__ bias,
    const float* __restrict__ g, const float* __restrict__ b,
    const float* __restrict__ m, const float* __restrict__ v,
    const float* __restrict__ Wc, const float* __restrict__ bc,
    float* __restrict__ out) {
    int lane = threadIdx.x & 63;
    int i = blockIdx.x * 4 + (threadIdx.x >> 6);
    if (i >= NN) return;
    int qw = lane >> 4;
    int c4 = lane & 15;
    uint2 xru = *(const uint2*)&xlr[(size_t)i * 128 + 64 + 4 * c4];
    float xr0 = LOF(xru.x), xr1 = HIF(xru.x), xr2 = LOF(xru.y), xr3 = HIF(xru.y);
    float4 at = *(const float4*)&att[4 * c4];
    float4 a6 = make_float4(at.x * (0.6f * LOG2E), at.y * (0.6f * LOG2E),
                            at.z * (0.6f * LOG2E), at.w * (0.6f * LOG2E));
    float4 a4 = make_float4(at.x * (0.4f * LOG2E), at.y * (0.4f * LOG2E),
                            at.z * (0.4f * LOG2E), at.w * (0.4f * LOG2E));
    int row = rowstart[i], end = rowstart[i + 1];
    float a0 = 0.f, a1 = 0.f, a2 = 0.f, a3 = 0.f, s = 0.f;
    int j = row;
    for (; j + 16 <= end; j += 16) {
        int src[4];
        uint2 u[4];
#pragma unroll
        for (int k = 0; k < 4; k++) src[k] = ssrc[j + 4 * k + qw];
#pragma unroll
        for (int k = 0; k < 4; k++)
            u[k] = *(const uint2*)&xlr[(size_t)src[k] * 128 + 4 * c4];
        float d[4], f0[4], f1[4], f2[4], f3[4];
#pragma unroll
        for (int k = 0; k < 4; k++) {
            f0[k] = LOF(u[k].x); f1[k] = HIF(u[k].x);
            f2[k] = LOF(u[k].y); f3[k] = HIF(u[k].y);
            float t0 = f0[k] + xr0, t1 = f1[k] + xr1;
            float t2 = f2[k] + xr2, t3 = f3[k] + xr3;
            float dd = fmaf(a6.x, t0, a4.x * fabsf(t0));
            dd = fmaf(a6.y, t1, fmaf(a4.y, fabsf(t1), dd));
            dd = fmaf(a6.z, t2, fmaf(a4.z, fabsf(t2), dd));
            dd = fmaf(a6.w, t3, fmaf(a4.w, fabsf(t3), dd));
            d[k] = dd;
        }
#pragma unroll
        for (int o = 1; o <= 8; o <<= 1) {
#pragma unroll
            for (int k = 0; k < 4; k++) d[k] += __shfl_xor(d[k], o, 64);
        }
#pragma unroll
        for (int k = 0; k < 4; k++) {
            float p = exp2f(d[k]);
            a0 += p * f0[k]; a1 += p * f1[k];
            a2 += p * f2[k]; a3 += p * f3[k];
            s += p;
        }
    }
    if (j + 8 <= end) {
        int src2[2];
        uint2 u2[2];
#pragma unroll
        for (int k = 0; k < 2; k++) src2[k] = ssrc[j + 4 * k + qw];
#pragma unroll
        for (int k = 0; k < 2; k++)
            u2[k] = *(const uint2*)&xlr[(size_t)src2[k] * 128 + 4 * c4];
#pragma unroll
        for (int k = 0; k < 2; k++) {
            float f0 = LOF(u2[k].x), f1 = HIF(u2[k].x), f2 = LOF(u2[k].y), f3 = HIF(u2[k].y);
            float t0 = f0 + xr0, t1 = f1 + xr1, t2 = f2 + xr2, t3 = f3 + xr3;
            float dd = fmaf(a6.x, t0, a4.x * fabsf(t0));
            dd = fmaf(a6.y, t1, fmaf(a4.y, fabsf(t1), dd));
            dd = fmaf(a6.z, t2, fmaf(a4.z, fabsf(t2), dd));
            dd = fmaf(a6.w, t3, fmaf(a4.w, fabsf(t3), dd));
            dd += __shfl_xor(dd, 1, 64);
            dd += __shfl_xor(dd, 2, 64);
            dd += __shfl_xor(dd, 4, 64);
            dd += __shfl_xor(dd, 8, 64);
            float p = exp2f(dd);
            a0 += p * f0; a1 += p * f1; a2 += p * f2; a3 += p * f3;
            s += p;
        }
        j += 8;
    }
    for (; j < end; j += 4) {
        int je = j + qw;
        bool valid = je < end;
        int src = valid ? ssrc[je] : i;
        uint2 uu = *(const uint2*)&xlr[(size_t)src * 128 + 4 * c4];
        float f0 = LOF(uu.x), f1 = HIF(uu.x), f2 = LOF(uu.y), f3 = HIF(uu.y);
        float t0 = f0 + xr0, t1 = f1 + xr1, t2 = f2 + xr2, t3 = f3 + xr3;
        float dd = fmaf(a6.x, t0, a4.x * fabsf(t0));
        dd = fmaf(a6.y, t1, fmaf(a4.y, fabsf(t1), dd));
        dd = fmaf(a6.z, t2, fmaf(a4.z, fabsf(t2), dd));
        dd = fmaf(a6.w, t3, fmaf(a4.w, fabsf(t3), dd));
        dd += __shfl_xor(dd, 1, 64);
        dd += __shfl_xor(dd, 2, 64);
        dd += __shfl_xor(dd, 4, 64);
        dd += __shfl_xor(dd, 8, 64);
        float p = valid ? exp2f(dd) : 0.f;
        a0 += p * f0; a1 += p * f1; a2 += p * f2; a3 += p * f3;
        s += p;
    }
    // combine the 4 quarter-wave edge slots
#pragma unroll
    for (int o = 16; o <= 32; o <<= 1) {
        a0 += __shfl_xor(a0, o, 64);
        a1 += __shfl_xor(a1, o, 64);
        a2 += __shfl_xor(a2, o, 64);
        a3 += __shfl_xor(a3, o, 64);
        s  += __shfl_xor(s, o, 64);
    }
    float inv = 1.f / s;
    float4 bb = *(const float4*)&bias[4 * c4];
    float4 mm = *(const float4*)&m[4 * c4];
    float4 vv = *(const float4*)&v[4 * c4];
    float4 gg = *(const float4*)&g[4 * c4];
    float4 b2 = *(const float4*)&b[4 * c4];
    float o0 = a0 * inv + bb.x, o1 = a1 * inv + bb.y;
    float o2 = a2 * inv + bb.z, o3 = a3 * inv + bb.w;
    o0 = (o0 - mm.x) * rsqrtf(vv.x + 1e-5f) * gg.x + b2.x;
    o1 = (o1 - mm.y) * rsqrtf(vv.y + 1e-5f) * gg.y + b2.y;
    o2 = (o2 - mm.z) * rsqrtf(vv.z + 1e-5f) * gg.z + b2.z;
    o3 = (o3 - mm.w) * rsqrtf(vv.w + 1e-5f) * gg.w + b2.w;
    o0 = ELU(o0); o1 = ELU(o1); o2 = ELU(o2); o3 = ELU(o3);
    float4 wc = *(const float4*)&Wc[4 * c4];
    float z = o0 * wc.x + o1 * wc.y + o2 * wc.z + o3 * wc.w;
    z += __shfl_xor(z, 1, 64);
    z += __shfl_xor(z, 2, 64);
    z += __shfl_xor(z, 4, 64);
    z += __shfl_xor(z, 8, 64);
    if (lane == 0) out[i] = 1.f / (1.f + __expf(-(z + bc[0])));
}

// ---------------- launch ----------------

extern "C" void kernel_launch(void* const* d_in, const int* in_sizes, int n_in,
                              void* d_out, int out_size, void* d_ws, size_t ws_size,
                              hipStream_t stream) {
    const float* x    = (const float*)d_in[0];
    const int*   ei   = (const int*)d_in[1];
    const float* W1l  = (const float*)d_in[2];
    const float* b1l  = (const float*)d_in[3];
    const float* W1r  = (const float*)d_in[4];
    const float* b1r  = (const float*)d_in[5];
    const float* att1 = (const float*)d_in[6];
    const float* bias1= (const float*)d_in[7];
    const float* bn1g = (const float*)d_in[8];
    const float* bn1b = (const float*)d_in[9];
    const float* bn1m = (const float*)d_in[10];
    const float* bn1v = (const float*)d_in[11];
    const float* W2l  = (const float*)d_in[12];
    const float* b2l  = (const float*)d_in[13];
    const float* W2r  = (const float*)d_in[14];
    const float* b2r  = (const float*)d_in[15];
    const float* att2 = (const float*)d_in[16];
    const float* bias2= (const float*)d_in[17];
    const float* bn2g = (const float*)d_in[18];
    const float* bn2b = (const float*)d_in[19];
    const float* bn2m = (const float*)d_in[20];
    const float* bn2v = (const float*)d_in[21];
    const float* Wc   = (const float*)d_in[22];
    const float* bc   = (const float*)d_in[23];
    float* out = (float*)d_out;

    char* ws = (char*)d_ws;
    size_t off = 0;
    auto alloc = [&](size_t bytes) {
        size_t o = off;
        off += (bytes + 255) & ~(size_t)255;
        return o;
    };
    ushort_t* xb    = (ushort_t*)(ws + alloc((size_t)(NN + 128) * 256 * 2));
    ushort_t* xlr1  = (ushort_t*)(ws + alloc((size_t)NN * 256 * 2));  // reused as xlr2
    ushort_t* h1b   = (ushort_t*)(ws + alloc((size_t)(NN + 128) * 128 * 2));
    ushort_t* Wt1   = (ushort_t*)(ws + alloc((size_t)256 * 256 * 2));
    float*    biasf1= (float*)(ws + alloc(256 * 4));
    ushort_t* Wt2   = (ushort_t*)(ws + alloc((size_t)128 * 128 * 2));
    float*    biasf2= (float*)(ws + alloc(128 * 4));
    int* deg8     = (int*)(ws + alloc((size_t)NREP * NN * 4));
    int* degt     = (int*)(ws + alloc((size_t)NN * 4));
    int* incl     = (int*)(ws + alloc((size_t)NN * 4));
    int* rowstart = (int*)(ws + alloc((size_t)(NN + 1) * 4));
    int* off8     = (int*)(ws + alloc((size_t)NREP * NN * 4));
    int* totals   = (int*)(ws + alloc(64 * 4));
    int* rank     = (int*)(ws + alloc((size_t)TE * 4));
    int* ssrc     = (int*)(ws + alloc((size_t)TE * 4));
    ushort_t* xlr2 = xlr1;

    // deg8 = 0
    hipMemsetAsync(deg8, 0, (size_t)NREP * NN * 4, stream);

    // K1: count+rank (XCD-sharded) | cast x->bf16 | prep W1 | prep W2
    k_stage1<<<NB_K1, 256, 0, stream>>>(ei, deg8, rank, x, xb,
                                        W1l, W1r, b1l, b1r, Wt1, biasf1,
                                        W2l, W2r, b2l, b2r, Wt2, biasf2);

    // scans (serial, small)
    k_scan1<<<NCHUNK, 1024, 0, stream>>>(deg8, degt, incl, totals);
    k_scan3<<<(NN + 255) / 256, 256, 0, stream>>>(incl, degt, deg8, totals,
                                                  rowstart, off8);

    // K2: GEMM layer-1 | scatter (independent; gemm blocks first)
    k_gemm1_scatter<<<NB_K2, 256, 0, stream>>>(xb, Wt1, biasf1, xlr1,
                                               ei, rank, off8, ssrc);

    // layer 1 fused
    k_fused1<<<(NN + 3) / 4, 256, 0, stream>>>(xlr1, rowstart, ssrc, att1, bias1,
                                               bn1g, bn1b, bn1m, bn1v, h1b);

    // layer 2 (+classifier)
    k_gemm2<<<(NN + 127) / 128, 256, 0, stream>>>(h1b, Wt2, biasf2, xlr2);
    k_fused2<<<(NN + 3) / 4, 256, 0, stream>>>(xlr2, rowstart, ssrc, att2, bias2,
                                               bn2g, bn2b, bn2m, bn2v, Wc, bc, out);
}